// Round 1
// baseline (480.704 us; speedup 1.0000x reference)
//
#include <hip/hip_runtime.h>

#define B_ 32
#define S_ 2048
#define H_ 1024

typedef __attribute__((ext_vector_type(8))) short short8;
typedef __attribute__((ext_vector_type(4))) float f32x4;

__device__ __forceinline__ unsigned short f2bf(float f) {
    unsigned u = __builtin_bit_cast(unsigned, f);
    u += 0x7FFFu + ((u >> 16) & 1u);
    return (unsigned short)(u >> 16);
}
__device__ __forceinline__ unsigned pk2(float x, float y) {
    return (unsigned)f2bf(x) | ((unsigned)f2bf(y) << 16);
}

// ---------- prep: Wh (K,N) fp32 -> WhT (N,K) bf16 ----------
__global__ void k_whT(const float* __restrict__ Wh, unsigned short* __restrict__ whT) {
    __shared__ float tile[64][65];
    int k0 = blockIdx.x * 64, n0 = blockIdx.y * 64;
    int tx = threadIdx.x, ty = threadIdx.y; // (64,4)
    #pragma unroll
    for (int i = 0; i < 16; ++i) {
        int r = ty + i * 4;
        tile[r][tx] = Wh[(size_t)(k0 + r) * H_ + n0 + tx];
    }
    __syncthreads();
    #pragma unroll
    for (int i = 0; i < 16; ++i) {
        int r = ty + i * 4;
        whT[(size_t)(n0 + r) * H_ + k0 + tx] = f2bf(tile[tx][r]);
    }
}

// ---------- prep: decp[b][n] = sum_h ds[b][h]*Ws[h][n] + bs[n] + bh[n] ----------
__global__ void k_decp(const float* __restrict__ ds, const float* __restrict__ Ws,
                       const float* __restrict__ bs, const float* __restrict__ bh,
                       float* __restrict__ decp) {
    int n = blockIdx.x * 256 + threadIdx.x;
    int b = blockIdx.y;
    float a0 = 0.f, a1 = 0.f, a2 = 0.f, a3 = 0.f;
    for (int h = 0; h < H_; h += 4) {
        a0 += ds[b * H_ + h + 0] * Ws[(size_t)(h + 0) * H_ + n];
        a1 += ds[b * H_ + h + 1] * Ws[(size_t)(h + 1) * H_ + n];
        a2 += ds[b * H_ + h + 2] * Ws[(size_t)(h + 2) * H_ + n];
        a3 += ds[b * H_ + h + 3] * Ws[(size_t)(h + 3) * H_ + n];
    }
    decp[b * H_ + n] = a0 + a1 + a2 + a3 + bs[n] + bh[n];
}

// ---------- prep: covp[b] = sum_s cov[b][s]*Wc[s] + bc ----------
__global__ void k_covp(const float* __restrict__ cov, const float* __restrict__ Wc,
                       const float* __restrict__ bc, float* __restrict__ covp) {
    int b = blockIdx.x, t = threadIdx.x;
    float p = 0.f;
    for (int s = t; s < S_; s += 256) p += cov[b * S_ + s] * Wc[s];
    for (int off = 32; off; off >>= 1) p += __shfl_down(p, off);
    __shared__ float w[4];
    if ((t & 63) == 0) w[t >> 6] = p;
    __syncthreads();
    if (t == 0) covp[b] = w[0] + w[1] + w[2] + w[3] + bc[0];
}

// ---------- fused GEMM + tanh + V-dot -> scores (atomicAdd) ----------
// A: enc (M=65536 x K=1024) fp32, converted to bf16 during staging
// B: whT (N=1024 x K=1024) bf16, pre-transposed
// LDS layout: fragment-ready 16B chunks; chunk (blk*64+lane) holds
// row blk*16+(lane&15), k-slice (lane>>4)*8..+8 -> lane-linear ds_read_b128.
__global__ __launch_bounds__(256, 2) void k_gemm_score(
    const float* __restrict__ enc, const unsigned short* __restrict__ whT,
    const float* __restrict__ decp, const float* __restrict__ covp,
    const float* __restrict__ V, float* __restrict__ scores)
{
    __shared__ uint4 lds[2][1024]; // [buf][A:0..511 | B:512..1023]

    int bid = blockIdx.x;
    // XCD-chunked swizzle: 8 N-tiles sharing an A-stripe -> same XCD L2
    int xcd = bid & 7, idx = bid >> 3;
    int tile_m = xcd * 64 + (idx >> 3);
    int tile_n = idx & 7;

    int t = threadIdx.x, lane = t & 63, wid = t >> 6;
    int wm = wid >> 1, wn = wid & 1;
    size_t row0 = (size_t)tile_m * 128;
    int n0 = tile_n * 128;

    // staging coords: this thread owns chunks c0=t and c1=t+256 (for A and B each)
    int c0 = t, c1 = t + 256;
    int blk0 = c0 >> 6, l0 = c0 & 63, r0 = blk0 * 16 + (l0 & 15), ks0 = l0 >> 4;
    int blk1 = c1 >> 6, l1 = c1 & 63, r1 = blk1 * 16 + (l1 & 15), ks1 = l1 >> 4;

    const float* pa0 = enc + (row0 + r0) * H_ + ks0 * 8;
    const float* pa1 = enc + (row0 + r1) * H_ + ks1 * 8;
    const unsigned short* pb0 = whT + (size_t)(n0 + r0) * H_ + ks0 * 8;
    const unsigned short* pb1 = whT + (size_t)(n0 + r1) * H_ + ks1 * 8;

    f32x4 acc[4][4] = {};
    float4 a0x, a0y, a1x, a1y;
    uint4 b0, b1;

    auto LOAD = [&](int kt) {
        const float4* q0 = (const float4*)(pa0 + kt * 32);
        a0x = q0[0]; a0y = q0[1];
        const float4* q1 = (const float4*)(pa1 + kt * 32);
        a1x = q1[0]; a1y = q1[1];
        b0 = *(const uint4*)(pb0 + kt * 32);
        b1 = *(const uint4*)(pb1 + kt * 32);
    };
    auto WRITE = [&](int buf) {
        lds[buf][c0] = make_uint4(pk2(a0x.x, a0x.y), pk2(a0x.z, a0x.w),
                                  pk2(a0y.x, a0y.y), pk2(a0y.z, a0y.w));
        lds[buf][c1] = make_uint4(pk2(a1x.x, a1x.y), pk2(a1x.z, a1x.w),
                                  pk2(a1y.x, a1y.y), pk2(a1y.z, a1y.w));
        lds[buf][512 + c0] = b0;
        lds[buf][512 + c1] = b1;
    };

    LOAD(0); WRITE(0); __syncthreads();
    int cur = 0;
    for (int kt = 0; kt < 32; ++kt) {
        if (kt < 31) LOAD(kt + 1);
        const short8* LA = (const short8*)&lds[cur][0];
        const short8* LB = (const short8*)&lds[cur][512];
        short8 af[4], bf[4];
        #pragma unroll
        for (int m = 0; m < 4; ++m) af[m] = LA[(wm * 4 + m) * 64 + lane];
        #pragma unroll
        for (int n = 0; n < 4; ++n) bf[n] = LB[(wn * 4 + n) * 64 + lane];
        #pragma unroll
        for (int m = 0; m < 4; ++m)
            #pragma unroll
            for (int n = 0; n < 4; ++n)
                acc[m][n] = __builtin_amdgcn_mfma_f32_16x16x32_bf16(af[m], bf[n], acc[m][n], 0, 0, 0);
        if (kt < 31) WRITE(cur ^ 1);
        __syncthreads();
        cur ^= 1;
    }

    // epilogue: x = acc + decp[b][c] + covp[b]; tanh(x)*V[c]; row-reduce; atomicAdd
    int colb = n0 + wn * 64 + (lane & 15);
    size_t rowg = row0 + (size_t)wm * 64;
    int b = (int)(rowg >> 11); // / S_
    float cb = covp[b];
    float vv[4], dp[4];
    #pragma unroll
    for (int n = 0; n < 4; ++n) {
        int c = colb + n * 16;
        vv[n] = V[c];
        dp[n] = decp[b * H_ + c] + cb;
    }
    #pragma unroll
    for (int m = 0; m < 4; ++m) {
        float rs[4] = {0.f, 0.f, 0.f, 0.f};
        #pragma unroll
        for (int n = 0; n < 4; ++n) {
            f32x4 A = acc[m][n];
            #pragma unroll
            for (int j = 0; j < 4; ++j) {
                float x = A[j] + dp[n];
                float e = __expf(2.f * x);
                float th = 1.f - 2.f / (e + 1.f); // robust tanh (inf-safe)
                rs[j] += th * vv[n];
            }
        }
        #pragma unroll
        for (int off = 1; off < 16; off <<= 1) {
            #pragma unroll
            for (int j = 0; j < 4; ++j) rs[j] += __shfl_xor(rs[j], off);
        }
        if ((lane & 15) == 0) {
            size_t r = rowg + m * 16 + (lane >> 4) * 4;
            #pragma unroll
            for (int j = 0; j < 4; ++j) atomicAdd(&scores[r + j], rs[j]);
        }
    }
}

// ---------- softmax over S per b; writes attn and coverage_new ----------
__global__ void k_softmax(const float* __restrict__ scores, const float* __restrict__ cov,
                          float* __restrict__ out) {
    int b = blockIdx.x, t = threadIdx.x;
    float* attn = out + B_ * H_;
    float* covn = out + B_ * H_ + B_ * S_;
    float v[8];
    float mx = -1e30f;
    #pragma unroll
    for (int i = 0; i < 8; ++i) {
        v[i] = scores[b * S_ + i * 256 + t];
        mx = fmaxf(mx, v[i]);
    }
    for (int off = 32; off; off >>= 1) mx = fmaxf(mx, __shfl_xor(mx, off));
    __shared__ float wsm[4], wss[4];
    if ((t & 63) == 0) wsm[t >> 6] = mx;
    __syncthreads();
    mx = fmaxf(fmaxf(wsm[0], wsm[1]), fmaxf(wsm[2], wsm[3]));
    float sum = 0.f;
    #pragma unroll
    for (int i = 0; i < 8; ++i) { v[i] = __expf(v[i] - mx); sum += v[i]; }
    for (int off = 32; off; off >>= 1) sum += __shfl_xor(sum, off);
    if ((t & 63) == 0) wss[t >> 6] = sum;
    __syncthreads();
    sum = wss[0] + wss[1] + wss[2] + wss[3];
    float inv = 1.f / sum;
    #pragma unroll
    for (int i = 0; i < 8; ++i) {
        int s = i * 256 + t;
        float a = v[i] * inv;
        attn[b * S_ + s] = a;
        covn[b * S_ + s] = cov[b * S_ + s] + a;
    }
}

// ---------- context[b][h] = sum_s attn[b][s]*enc[b][s][h] ----------
__global__ void k_context(const float* __restrict__ enc, const float* __restrict__ attn,
                          float* __restrict__ ctx) {
    int b = blockIdx.y, chunk = blockIdx.x; // 16 chunks x 128 s
    int t = threadIdx.x;
    __shared__ float sa[128];
    int s0 = chunk * 128;
    if (t < 128) sa[t] = attn[b * S_ + s0 + t];
    __syncthreads();
    float4 acc = {0.f, 0.f, 0.f, 0.f};
    const float4* e = (const float4*)(enc + ((size_t)b * S_ + s0) * H_) + t;
    #pragma unroll 4
    for (int s = 0; s < 128; ++s) {
        float4 x = e[(size_t)s * (H_ / 4)];
        float a = sa[s];
        acc.x += a * x.x; acc.y += a * x.y; acc.z += a * x.z; acc.w += a * x.w;
    }
    float* c = ctx + b * H_ + t * 4;
    atomicAdd(c + 0, acc.x); atomicAdd(c + 1, acc.y);
    atomicAdd(c + 2, acc.z); atomicAdd(c + 3, acc.w);
}

extern "C" void kernel_launch(void* const* d_in, const int* in_sizes, int n_in,
                              void* d_out, int out_size, void* d_ws, size_t ws_size,
                              hipStream_t stream) {
    (void)in_sizes; (void)n_in; (void)out_size; (void)ws_size;
    const float* ds  = (const float*)d_in[0];
    const float* enc = (const float*)d_in[1];
    const float* cov = (const float*)d_in[2];
    const float* Wh  = (const float*)d_in[3];
    const float* bh  = (const float*)d_in[4];
    const float* Ws  = (const float*)d_in[5];
    const float* bs  = (const float*)d_in[6];
    const float* V   = (const float*)d_in[7];
    // d_in[8] = bv: constant shift, softmax-invariant -> unused
    const float* Wc  = (const float*)d_in[9];
    const float* bc  = (const float*)d_in[10];
    float* out = (float*)d_out;

    float* ws_scores = (float*)d_ws;                      // 65536 f32
    float* ws_decp   = ws_scores + B_ * S_;               // 32768 f32
    float* ws_covp   = ws_decp + B_ * H_;                 // 64 f32 (32 used)
    unsigned short* ws_whT = (unsigned short*)(ws_covp + 64); // 1M bf16 (2MB)

    hipMemsetAsync(ws_scores, 0, B_ * S_ * sizeof(float), stream);
    hipMemsetAsync(out, 0, B_ * H_ * sizeof(float), stream); // context accumulators

    k_whT<<<dim3(16, 16), dim3(64, 4), 0, stream>>>(Wh, ws_whT);
    k_decp<<<dim3(4, 32), 256, 0, stream>>>(ds, Ws, bs, bh, ws_decp);
    k_covp<<<32, 256, 0, stream>>>(cov, Wc, bc, ws_covp);
    k_gemm_score<<<4096, 256, 0, stream>>>(enc, ws_whT, ws_decp, ws_covp, V, ws_scores);
    k_softmax<<<32, 256, 0, stream>>>(ws_scores, cov, out);
    k_context<<<dim3(16, 32), 256, 0, stream>>>(enc, out + B_ * H_, out);
}

// Round 2
// 437.399 us; speedup vs baseline: 1.0990x; 1.0990x over previous
//
#include <hip/hip_runtime.h>

#define B_ 32
#define S_ 2048
#define H_ 1024

typedef __attribute__((ext_vector_type(8))) short short8;
typedef __attribute__((ext_vector_type(4))) float f32x4;
typedef __attribute__((ext_vector_type(4))) unsigned short u16x4;

__device__ __forceinline__ unsigned short f2bf(float f) {
    unsigned u = __builtin_bit_cast(unsigned, f);
    u += 0x7FFFu + ((u >> 16) & 1u);
    return (unsigned short)(u >> 16);
}
__device__ __forceinline__ unsigned pk2(float x, float y) {
    return (unsigned)f2bf(x) | ((unsigned)f2bf(y) << 16);
}
__device__ __forceinline__ float bf2f(unsigned short u) {
    unsigned x = ((unsigned)u) << 16;
    return __builtin_bit_cast(float, x);
}
__device__ __forceinline__ void gload16(const void* g, void* l) {
    __builtin_amdgcn_global_load_lds((const __attribute__((address_space(1))) void*)g,
                                     (__attribute__((address_space(3))) void*)l, 16, 0, 0);
}

// ---------- enc fp32 -> bf16 (grid-stride, 8 elems/thread/iter) ----------
__global__ void k_cvt(const float* __restrict__ in, uint4* __restrict__ out, int ngroups) {
    int i = blockIdx.x * blockDim.x + threadIdx.x;
    int stride = gridDim.x * blockDim.x;
    for (; i < ngroups; i += stride) {
        const float4* p = (const float4*)in + (size_t)i * 2;
        float4 x = p[0], y = p[1];
        out[i] = make_uint4(pk2(x.x, x.y), pk2(x.z, x.w), pk2(y.x, y.y), pk2(y.z, y.w));
    }
}

// ---------- prep: Wh (K,N) fp32 -> WhT (N,K) bf16 ----------
__global__ void k_whT(const float* __restrict__ Wh, unsigned short* __restrict__ whT) {
    __shared__ float tile[64][65];
    int k0 = blockIdx.x * 64, n0 = blockIdx.y * 64;
    int tx = threadIdx.x, ty = threadIdx.y; // (64,4)
    #pragma unroll
    for (int i = 0; i < 16; ++i) {
        int r = ty + i * 4;
        tile[r][tx] = Wh[(size_t)(k0 + r) * H_ + n0 + tx];
    }
    __syncthreads();
    #pragma unroll
    for (int i = 0; i < 16; ++i) {
        int r = ty + i * 4;
        whT[(size_t)(n0 + r) * H_ + k0 + tx] = f2bf(tile[tx][r]);
    }
}

// ---------- prep: decp[b][n] = ds[b]@Ws[:,n] + bs[n] + bh[n] ----------
__global__ void k_decp(const float* __restrict__ ds, const float* __restrict__ Ws,
                       const float* __restrict__ bs, const float* __restrict__ bh,
                       float* __restrict__ decp) {
    int n = blockIdx.x * 256 + threadIdx.x;
    int b = blockIdx.y;
    float a0 = 0.f, a1 = 0.f, a2 = 0.f, a3 = 0.f;
    for (int h = 0; h < H_; h += 4) {
        a0 += ds[b * H_ + h + 0] * Ws[(size_t)(h + 0) * H_ + n];
        a1 += ds[b * H_ + h + 1] * Ws[(size_t)(h + 1) * H_ + n];
        a2 += ds[b * H_ + h + 2] * Ws[(size_t)(h + 2) * H_ + n];
        a3 += ds[b * H_ + h + 3] * Ws[(size_t)(h + 3) * H_ + n];
    }
    decp[b * H_ + n] = a0 + a1 + a2 + a3 + bs[n] + bh[n];
}

// ---------- prep: covp[b] = cov[b]@Wc + bc ----------
__global__ void k_covp(const float* __restrict__ cov, const float* __restrict__ Wc,
                       const float* __restrict__ bc, float* __restrict__ covp) {
    int b = blockIdx.x, t = threadIdx.x;
    float p = 0.f;
    for (int s = t; s < S_; s += 256) p += cov[b * S_ + s] * Wc[s];
    for (int off = 32; off; off >>= 1) p += __shfl_down(p, off);
    __shared__ float w[4];
    if ((t & 63) == 0) w[t >> 6] = p;
    __syncthreads();
    if (t == 0) covp[b] = w[0] + w[1] + w[2] + w[3] + bc[0];
}

// ---------- shared epilogue: tanh + V-dot + row-reduce + atomicAdd ----------
__device__ __forceinline__ void score_epilogue(
    f32x4 acc[4][4], int n0, int wm, int wn, int lane, size_t row0,
    const float* __restrict__ decp, const float* __restrict__ covp,
    const float* __restrict__ V, float* __restrict__ scores)
{
    int colb = n0 + wn * 64 + (lane & 15);
    size_t rowg = row0 + (size_t)wm * 64;
    int b = (int)(rowg >> 11); // / S_
    float cb = covp[b];
    float vv[4], dp[4];
    #pragma unroll
    for (int n = 0; n < 4; ++n) {
        int c = colb + n * 16;
        vv[n] = V[c];
        dp[n] = decp[b * H_ + c] + cb;
    }
    #pragma unroll
    for (int m = 0; m < 4; ++m) {
        float rs[4] = {0.f, 0.f, 0.f, 0.f};
        #pragma unroll
        for (int n = 0; n < 4; ++n) {
            f32x4 A = acc[m][n];
            #pragma unroll
            for (int j = 0; j < 4; ++j) {
                float x = A[j] + dp[n];
                float e = __expf(2.f * x);
                float th = 1.f - 2.f / (e + 1.f); // inf-safe tanh
                rs[j] += th * vv[n];
            }
        }
        #pragma unroll
        for (int off = 1; off < 16; off <<= 1) {
            #pragma unroll
            for (int j = 0; j < 4; ++j) rs[j] += __shfl_xor(rs[j], off);
        }
        if ((lane & 15) == 0) {
            size_t r = rowg + m * 16 + (lane >> 4) * 4;
            #pragma unroll
            for (int j = 0; j < 4; ++j) atomicAdd(&scores[r + j], rs[j]);
        }
    }
}

// ---------- main GEMM (m97 structure): A=encBF (M x K), B=whT (N x K), both bf16 ----------
// LDS chunk c (1KB) = 16x32 subtile, lane-linear: lane l <-> (row c*16+(l&15), k (l>>4)*8..+8)
// -> global_load_lds dest is chunk base + lane*16; ds_read_b128 at chunk base + lane*16.
__global__ __launch_bounds__(256) void k_gemm_bf16(
    const unsigned short* __restrict__ A, const unsigned short* __restrict__ Bm,
    const float* __restrict__ decp, const float* __restrict__ covp,
    const float* __restrict__ V, float* __restrict__ scores)
{
    __shared__ char lds[32768]; // [2 bufs][A 8KB | B 8KB]

    int bid = blockIdx.x;
    // XCD-chunked bijective swizzle (4096 % 8 == 0): tiles sharing an A-stripe
    // (8 consecutive tile_n) stay on one XCD's L2.
    int xcd = bid & 7, local = bid >> 3;
    int T = xcd * 512 + local;
    int tile_m = T >> 3, tile_n = T & 7;
    size_t row0 = (size_t)tile_m * 128;
    int n0 = tile_n * 128;

    int t = threadIdx.x, lane = t & 63, wid = t >> 6;
    int wm = wid >> 1, wn = wid & 1;
    int lrow = lane & 15, lk = (lane >> 4) * 8;

    // each wave stages A chunks {2wid, 2wid+1} and B chunks {2wid, 2wid+1}
    const unsigned short* gA0 = A + (row0 + (size_t)(wid * 32) + lrow) * H_ + lk;
    const unsigned short* gA1 = gA0 + (size_t)16 * H_;
    const unsigned short* gB0 = Bm + ((size_t)(n0 + wid * 32 + lrow)) * H_ + lk;
    const unsigned short* gB1 = gB0 + (size_t)16 * H_;

    f32x4 acc[4][4] = {};

    #define STAGE(buf, kt) do { \
        char* lb = lds + (buf) * 16384; \
        gload16(gA0 + (kt) * 32, lb + (2 * wid) * 1024); \
        gload16(gA1 + (kt) * 32, lb + (2 * wid + 1) * 1024); \
        gload16(gB0 + (kt) * 32, lb + 8192 + (2 * wid) * 1024); \
        gload16(gB1 + (kt) * 32, lb + 8192 + (2 * wid + 1) * 1024); \
    } while (0)

    STAGE(0, 0);
    int cur = 0;
    for (int kt = 0; kt < 32; ++kt) {
        __syncthreads();                 // drains vmcnt -> buf[cur] ready; prev reads done
        if (kt < 31) STAGE(cur ^ 1, kt + 1);
        const char* base = lds + cur * 16384;
        short8 af[4], bf[4];
        #pragma unroll
        for (int m = 0; m < 4; ++m)
            af[m] = *(const short8*)(base + (wm * 4 + m) * 1024 + lane * 16);
        #pragma unroll
        for (int n = 0; n < 4; ++n)
            bf[n] = *(const short8*)(base + 8192 + (wn * 4 + n) * 1024 + lane * 16);
        #pragma unroll
        for (int m = 0; m < 4; ++m)
            #pragma unroll
            for (int n = 0; n < 4; ++n)
                acc[m][n] = __builtin_amdgcn_mfma_f32_16x16x32_bf16(af[m], bf[n], acc[m][n], 0, 0, 0);
        cur ^= 1;
    }
    #undef STAGE

    score_epilogue(acc, n0, wm, wn, lane, row0, decp, covp, V, scores);
}

// ---------- fallback GEMM (round-0: fp32 A reg-staged) ----------
__global__ __launch_bounds__(256, 2) void k_gemm_stage32(
    const float* __restrict__ enc, const unsigned short* __restrict__ whT,
    const float* __restrict__ decp, const float* __restrict__ covp,
    const float* __restrict__ V, float* __restrict__ scores)
{
    __shared__ uint4 lds[2][1024];
    int bid = blockIdx.x;
    int xcd = bid & 7, idx = bid >> 3;
    int tile_m = xcd * 64 + (idx >> 3);
    int tile_n = idx & 7;
    int t = threadIdx.x, lane = t & 63, wid = t >> 6;
    int wm = wid >> 1, wn = wid & 1;
    size_t row0 = (size_t)tile_m * 128;
    int n0 = tile_n * 128;
    int c0 = t, c1 = t + 256;
    int blk0 = c0 >> 6, l0 = c0 & 63, r0 = blk0 * 16 + (l0 & 15), ks0 = l0 >> 4;
    int blk1 = c1 >> 6, l1 = c1 & 63, r1 = blk1 * 16 + (l1 & 15), ks1 = l1 >> 4;
    const float* pa0 = enc + (row0 + r0) * H_ + ks0 * 8;
    const float* pa1 = enc + (row0 + r1) * H_ + ks1 * 8;
    const unsigned short* pb0 = whT + (size_t)(n0 + r0) * H_ + ks0 * 8;
    const unsigned short* pb1 = whT + (size_t)(n0 + r1) * H_ + ks1 * 8;
    f32x4 acc[4][4] = {};
    float4 a0x, a0y, a1x, a1y;
    uint4 b0, b1;
    auto LOAD = [&](int kt) {
        const float4* q0 = (const float4*)(pa0 + kt * 32);
        a0x = q0[0]; a0y = q0[1];
        const float4* q1 = (const float4*)(pa1 + kt * 32);
        a1x = q1[0]; a1y = q1[1];
        b0 = *(const uint4*)(pb0 + kt * 32);
        b1 = *(const uint4*)(pb1 + kt * 32);
    };
    auto WRITE = [&](int buf) {
        lds[buf][c0] = make_uint4(pk2(a0x.x, a0x.y), pk2(a0x.z, a0x.w),
                                  pk2(a0y.x, a0y.y), pk2(a0y.z, a0y.w));
        lds[buf][c1] = make_uint4(pk2(a1x.x, a1x.y), pk2(a1x.z, a1x.w),
                                  pk2(a1y.x, a1y.y), pk2(a1y.z, a1y.w));
        lds[buf][512 + c0] = b0;
        lds[buf][512 + c1] = b1;
    };
    LOAD(0); WRITE(0); __syncthreads();
    int cur = 0;
    for (int kt = 0; kt < 32; ++kt) {
        if (kt < 31) LOAD(kt + 1);
        const short8* LA = (const short8*)&lds[cur][0];
        const short8* LB = (const short8*)&lds[cur][512];
        short8 af[4], bf[4];
        #pragma unroll
        for (int m = 0; m < 4; ++m) af[m] = LA[(wm * 4 + m) * 64 + lane];
        #pragma unroll
        for (int n = 0; n < 4; ++n) bf[n] = LB[(wn * 4 + n) * 64 + lane];
        #pragma unroll
        for (int m = 0; m < 4; ++m)
            #pragma unroll
            for (int n = 0; n < 4; ++n)
                acc[m][n] = __builtin_amdgcn_mfma_f32_16x16x32_bf16(af[m], bf[n], acc[m][n], 0, 0, 0);
        if (kt < 31) WRITE(cur ^ 1);
        __syncthreads();
        cur ^= 1;
    }
    score_epilogue(acc, n0, wm, wn, lane, row0, decp, covp, V, scores);
}

// ---------- softmax over S per b; writes attn and coverage_new ----------
__global__ void k_softmax(const float* __restrict__ scores, const float* __restrict__ cov,
                          float* __restrict__ out) {
    int b = blockIdx.x, t = threadIdx.x;
    float* attn = out + B_ * H_;
    float* covn = out + B_ * H_ + B_ * S_;
    float v[8];
    float mx = -1e30f;
    #pragma unroll
    for (int i = 0; i < 8; ++i) {
        v[i] = scores[b * S_ + i * 256 + t];
        mx = fmaxf(mx, v[i]);
    }
    for (int off = 32; off; off >>= 1) mx = fmaxf(mx, __shfl_xor(mx, off));
    __shared__ float wsm[4], wss[4];
    if ((t & 63) == 0) wsm[t >> 6] = mx;
    __syncthreads();
    mx = fmaxf(fmaxf(wsm[0], wsm[1]), fmaxf(wsm[2], wsm[3]));
    float sum = 0.f;
    #pragma unroll
    for (int i = 0; i < 8; ++i) { v[i] = __expf(v[i] - mx); sum += v[i]; }
    for (int off = 32; off; off >>= 1) sum += __shfl_xor(sum, off);
    if ((t & 63) == 0) wss[t >> 6] = sum;
    __syncthreads();
    sum = wss[0] + wss[1] + wss[2] + wss[3];
    float inv = 1.f / sum;
    #pragma unroll
    for (int i = 0; i < 8; ++i) {
        int s = i * 256 + t;
        float a = v[i] * inv;
        attn[b * S_ + s] = a;
        covn[b * S_ + s] = cov[b * S_ + s] + a;
    }
}

// ---------- context from bf16 enc ----------
__global__ void k_context_bf(const unsigned short* __restrict__ encBF,
                             const float* __restrict__ attn, float* __restrict__ ctx) {
    int b = blockIdx.y, chunk = blockIdx.x; // 16 chunks x 128 s
    int t = threadIdx.x;
    __shared__ float sa[128];
    int s0 = chunk * 128;
    if (t < 128) sa[t] = attn[b * S_ + s0 + t];
    __syncthreads();
    float4 acc = {0.f, 0.f, 0.f, 0.f};
    const unsigned short* e = encBF + ((size_t)(b * S_ + s0)) * H_ + t * 4;
    #pragma unroll 4
    for (int s = 0; s < 128; ++s) {
        u16x4 x = *(const u16x4*)(e + (size_t)s * H_);
        float a = sa[s];
        acc.x += a * bf2f(x[0]); acc.y += a * bf2f(x[1]);
        acc.z += a * bf2f(x[2]); acc.w += a * bf2f(x[3]);
    }
    float* c = ctx + b * H_ + t * 4;
    atomicAdd(c + 0, acc.x); atomicAdd(c + 1, acc.y);
    atomicAdd(c + 2, acc.z); atomicAdd(c + 3, acc.w);
}

// ---------- context from fp32 enc (fallback) ----------
__global__ void k_context_f32(const float* __restrict__ enc, const float* __restrict__ attn,
                              float* __restrict__ ctx) {
    int b = blockIdx.y, chunk = blockIdx.x;
    int t = threadIdx.x;
    __shared__ float sa[128];
    int s0 = chunk * 128;
    if (t < 128) sa[t] = attn[b * S_ + s0 + t];
    __syncthreads();
    float4 acc = {0.f, 0.f, 0.f, 0.f};
    const float4* e = (const float4*)(enc + ((size_t)b * S_ + s0) * H_) + t;
    #pragma unroll 4
    for (int s = 0; s < 128; ++s) {
        float4 x = e[(size_t)s * (H_ / 4)];
        float a = sa[s];
        acc.x += a * x.x; acc.y += a * x.y; acc.z += a * x.z; acc.w += a * x.w;
    }
    float* c = ctx + b * H_ + t * 4;
    atomicAdd(c + 0, acc.x); atomicAdd(c + 1, acc.y);
    atomicAdd(c + 2, acc.z); atomicAdd(c + 3, acc.w);
}

extern "C" void kernel_launch(void* const* d_in, const int* in_sizes, int n_in,
                              void* d_out, int out_size, void* d_ws, size_t ws_size,
                              hipStream_t stream) {
    (void)in_sizes; (void)n_in; (void)out_size;
    const float* ds  = (const float*)d_in[0];
    const float* enc = (const float*)d_in[1];
    const float* cov = (const float*)d_in[2];
    const float* Wh  = (const float*)d_in[3];
    const float* bh  = (const float*)d_in[4];
    const float* Ws  = (const float*)d_in[5];
    const float* bs  = (const float*)d_in[6];
    const float* V   = (const float*)d_in[7];
    // d_in[8] = bv: softmax-invariant constant -> unused
    const float* Wc  = (const float*)d_in[9];
    const float* bc  = (const float*)d_in[10];
    float* out = (float*)d_out;

    float* ws_scores = (float*)d_ws;                          // 65536 f32
    float* ws_decp   = ws_scores + B_ * S_;                   // 32768 f32
    float* ws_covp   = ws_decp + B_ * H_;                     // 64 f32
    unsigned short* ws_whT = (unsigned short*)(ws_covp + 64); // 1M bf16 (2MB)
    unsigned short* ws_encBF = ws_whT + (size_t)H_ * H_;      // 64M bf16 (128MB)
    const size_t need_full = ((char*)(ws_encBF + (size_t)B_ * S_ * H_)) - (char*)d_ws;

    hipMemsetAsync(ws_scores, 0, B_ * S_ * sizeof(float), stream);
    hipMemsetAsync(out, 0, B_ * H_ * sizeof(float), stream); // context accumulators

    k_whT<<<dim3(16, 16), dim3(64, 4), 0, stream>>>(Wh, ws_whT);
    k_decp<<<dim3(4, 32), 256, 0, stream>>>(ds, Ws, bs, bh, ws_decp);
    k_covp<<<32, 256, 0, stream>>>(cov, Wc, bc, ws_covp);

    if (ws_size >= need_full) {
        k_cvt<<<2048, 256, 0, stream>>>(enc, (uint4*)ws_encBF, (B_ * S_ * H_) / 8);
        k_gemm_bf16<<<4096, 256, 0, stream>>>(ws_encBF, ws_whT, ws_decp, ws_covp, V, ws_scores);
        k_softmax<<<32, 256, 0, stream>>>(ws_scores, cov, out);
        k_context_bf<<<dim3(16, 32), 256, 0, stream>>>(ws_encBF, out + B_ * H_, out);
    } else {
        k_gemm_stage32<<<4096, 256, 0, stream>>>(enc, ws_whT, ws_decp, ws_covp, V, ws_scores);
        k_softmax<<<32, 256, 0, stream>>>(ws_scores, cov, out);
        k_context_f32<<<dim3(16, 32), 256, 0, stream>>>(enc, out + B_ * H_, out);
    }
}

// Round 3
// 340.374 us; speedup vs baseline: 1.4123x; 1.2851x over previous
//
#include <hip/hip_runtime.h>

#define B_ 32
#define S_ 2048
#define H_ 1024

typedef __attribute__((ext_vector_type(8))) short short8;
typedef __attribute__((ext_vector_type(4))) float f32x4;
typedef __attribute__((ext_vector_type(4))) unsigned short u16x4;

__device__ __forceinline__ unsigned short f2bf(float f) {
    unsigned u = __builtin_bit_cast(unsigned, f);
    u += 0x7FFFu + ((u >> 16) & 1u);
    return (unsigned short)(u >> 16);
}
__device__ __forceinline__ unsigned pk2(float x, float y) {
    return (unsigned)f2bf(x) | ((unsigned)f2bf(y) << 16);
}
__device__ __forceinline__ float bf2f(unsigned short u) {
    unsigned x = ((unsigned)u) << 16;
    return __builtin_bit_cast(float, x);
}
__device__ __forceinline__ void gload16(const void* g, void* l) {
    __builtin_amdgcn_global_load_lds((const __attribute__((address_space(1))) void*)g,
                                     (__attribute__((address_space(3))) void*)l, 16, 0, 0);
}

#define WAITV(nstr) asm volatile("s_waitcnt vmcnt(" nstr ")" ::: "memory")

// ---------- enc fp32 -> bf16 ----------
__global__ void k_cvt(const float* __restrict__ in, uint4* __restrict__ out, int ngroups) {
    int i = blockIdx.x * blockDim.x + threadIdx.x;
    int stride = gridDim.x * blockDim.x;
    for (; i < ngroups; i += stride) {
        const float4* p = (const float4*)in + (size_t)i * 2;
        float4 x = p[0], y = p[1];
        out[i] = make_uint4(pk2(x.x, x.y), pk2(x.z, x.w), pk2(y.x, y.y), pk2(y.z, y.w));
    }
}

// ---------- prep: Wh (K,N) fp32 -> WhT (N,K) bf16 ----------
__global__ void k_whT(const float* __restrict__ Wh, unsigned short* __restrict__ whT) {
    __shared__ float tile[64][65];
    int k0 = blockIdx.x * 64, n0 = blockIdx.y * 64;
    int tx = threadIdx.x, ty = threadIdx.y; // (64,4)
    #pragma unroll
    for (int i = 0; i < 16; ++i) {
        int r = ty + i * 4;
        tile[r][tx] = Wh[(size_t)(k0 + r) * H_ + n0 + tx];
    }
    __syncthreads();
    #pragma unroll
    for (int i = 0; i < 16; ++i) {
        int r = ty + i * 4;
        whT[(size_t)(n0 + r) * H_ + k0 + tx] = f2bf(tile[tx][r]);
    }
}

// ---------- prep: decp[b][n] = ds[b]@Ws[:,n] + bs[n] + bh[n] ----------
__global__ void k_decp(const float* __restrict__ ds, const float* __restrict__ Ws,
                       const float* __restrict__ bs, const float* __restrict__ bh,
                       float* __restrict__ decp) {
    int n = blockIdx.x * 256 + threadIdx.x;
    int b = blockIdx.y;
    float a0 = 0.f, a1 = 0.f, a2 = 0.f, a3 = 0.f;
    for (int h = 0; h < H_; h += 4) {
        a0 += ds[b * H_ + h + 0] * Ws[(size_t)(h + 0) * H_ + n];
        a1 += ds[b * H_ + h + 1] * Ws[(size_t)(h + 1) * H_ + n];
        a2 += ds[b * H_ + h + 2] * Ws[(size_t)(h + 2) * H_ + n];
        a3 += ds[b * H_ + h + 3] * Ws[(size_t)(h + 3) * H_ + n];
    }
    decp[b * H_ + n] = a0 + a1 + a2 + a3 + bs[n] + bh[n];
}

// ---------- prep: covp[b] = cov[b]@Wc + bc ----------
__global__ void k_covp(const float* __restrict__ cov, const float* __restrict__ Wc,
                       const float* __restrict__ bc, float* __restrict__ covp) {
    int b = blockIdx.x, t = threadIdx.x;
    float p = 0.f;
    for (int s = t; s < S_; s += 256) p += cov[b * S_ + s] * Wc[s];
    for (int off = 32; off; off >>= 1) p += __shfl_down(p, off);
    __shared__ float w[4];
    if ((t & 63) == 0) w[t >> 6] = p;
    __syncthreads();
    if (t == 0) covp[b] = w[0] + w[1] + w[2] + w[3] + bc[0];
}

// ---------- main GEMM: 256x256 tile, 8 waves, BK=32, 4-deep counted-vmcnt ring ----------
// LDS chunk (1KB) = 16 rows x 32 k, lane-linear (== one MFMA A/B frag set for 16 rows):
// lane l <-> (row c*16+(l&15), k (l>>4)*8..+8). gload_lds dest = chunk + lane*16.
// Ring: buf[kt&3]; at iter top wait vmcnt(8) (tiles kt+1,kt+2 in flight), barrier.
// Tile kt+3 loads issued mid-iteration. vmcnt never drains to 0 until the tail.
__global__ __launch_bounds__(512, 2) void k_gemm_8w(
    const unsigned short* __restrict__ A, const unsigned short* __restrict__ Bm,
    const float* __restrict__ decp, const float* __restrict__ covp,
    const float* __restrict__ V, float* __restrict__ scores)
{
    __shared__ char lds[131072]; // 4 bufs x (A 16KB | B 16KB)

    int bid = blockIdx.x;
    // bijective XCD-chunked swizzle (1024 % 8 == 0): the 4 n-tiles sharing an
    // A-stripe are consecutive within one XCD's chunk.
    int xcd = bid & 7, local = bid >> 3;
    int T = xcd * 128 + local;
    int tile_m = T >> 2, tile_n = T & 3;
    size_t row0 = (size_t)tile_m * 256;
    int n0 = tile_n * 256;

    int t = threadIdx.x, lane = t & 63, wid = t >> 6; // 8 waves
    int wm = wid >> 2, wn = wid & 3;                  // 2 x 4 wave grid
    int lrow = lane & 15, lk = (lane >> 4) * 8;

    // wave w stages A-chunks {2w,2w+1} (rows 32w..32w+31) and same for B
    const unsigned short* gA0 = A + (row0 + (size_t)(wid * 32) + lrow) * H_ + lk;
    const unsigned short* gA1 = gA0 + (size_t)16 * H_;
    const unsigned short* gB0 = Bm + ((size_t)(n0 + wid * 32 + lrow)) * H_ + lk;
    const unsigned short* gB1 = gB0 + (size_t)16 * H_;

    f32x4 acc[8][4] = {};

    auto stageA = [&](int kt) {
        char* lb = lds + (kt & 3) * 32768;
        gload16(gA0 + kt * 32, lb + (2 * wid) * 1024);
        gload16(gA1 + kt * 32, lb + (2 * wid + 1) * 1024);
    };
    auto stageB = [&](int kt) {
        char* lb = lds + (kt & 3) * 32768 + 16384;
        gload16(gB0 + kt * 32, lb + (2 * wid) * 1024);
        gload16(gB1 + kt * 32, lb + (2 * wid + 1) * 1024);
    };

    auto body = [&](int kt, bool pf) {
        const char* base = lds + (kt & 3) * 32768;
        short8 af[8], bf[4];
        #pragma unroll
        for (int m = 0; m < 8; ++m)
            af[m] = *(const short8*)(base + (wm * 8 + m) * 1024 + lane * 16);
        bf[0] = *(const short8*)(base + 16384 + (wn * 4 + 0) * 1024 + lane * 16);
        bf[1] = *(const short8*)(base + 16384 + (wn * 4 + 1) * 1024 + lane * 16);
        if (pf) stageA(kt + 3);
        __builtin_amdgcn_s_setprio(1);
        #pragma unroll
        for (int m = 0; m < 8; ++m) {
            acc[m][0] = __builtin_amdgcn_mfma_f32_16x16x32_bf16(af[m], bf[0], acc[m][0], 0, 0, 0);
            acc[m][1] = __builtin_amdgcn_mfma_f32_16x16x32_bf16(af[m], bf[1], acc[m][1], 0, 0, 0);
        }
        __builtin_amdgcn_s_setprio(0);
        bf[2] = *(const short8*)(base + 16384 + (wn * 4 + 2) * 1024 + lane * 16);
        bf[3] = *(const short8*)(base + 16384 + (wn * 4 + 3) * 1024 + lane * 16);
        if (pf) stageB(kt + 3);
        __builtin_amdgcn_s_setprio(1);
        #pragma unroll
        for (int m = 0; m < 8; ++m) {
            acc[m][2] = __builtin_amdgcn_mfma_f32_16x16x32_bf16(af[m], bf[2], acc[m][2], 0, 0, 0);
            acc[m][3] = __builtin_amdgcn_mfma_f32_16x16x32_bf16(af[m], bf[3], acc[m][3], 0, 0, 0);
        }
        __builtin_amdgcn_s_setprio(0);
    };

    // prologue: tiles 0,1,2 in flight (12 loads/thread)
    stageA(0); stageB(0);
    stageA(1); stageB(1);
    stageA(2); stageB(2);

    for (int kt = 0; kt < 29; ++kt) {
        WAITV("8");                       // tile kt landed; kt+1,kt+2 (8 loads) in flight
        __builtin_amdgcn_s_barrier();
        body(kt, true);
    }
    WAITV("8"); __builtin_amdgcn_s_barrier(); body(29, false);
    WAITV("4"); __builtin_amdgcn_s_barrier(); body(30, false);
    WAITV("0"); __builtin_amdgcn_s_barrier(); body(31, false);

    // ---- epilogue: tanh + V-dot + 16-lane reduce + atomicAdd ----
    int colb = n0 + wn * 64 + (lane & 15);
    size_t rowg = row0 + (size_t)wm * 128;
    int b = (int)(row0 >> 11); // block entirely within one batch (2048 % 256 == 0)
    float cb = covp[b];
    float vv[4], dp[4];
    #pragma unroll
    for (int n = 0; n < 4; ++n) {
        int c = colb + n * 16;
        vv[n] = V[c];
        dp[n] = decp[b * H_ + c] + cb;
    }
    #pragma unroll
    for (int m = 0; m < 8; ++m) {
        float rs[4] = {0.f, 0.f, 0.f, 0.f};
        #pragma unroll
        for (int n = 0; n < 4; ++n) {
            f32x4 Aq = acc[m][n];
            #pragma unroll
            for (int j = 0; j < 4; ++j) {
                float x = Aq[j] + dp[n];
                float e = __expf(2.f * x);
                float th = 1.f - 2.f / (e + 1.f); // inf-safe tanh
                rs[j] += th * vv[n];
            }
        }
        #pragma unroll
        for (int off = 1; off < 16; off <<= 1) {
            #pragma unroll
            for (int j = 0; j < 4; ++j) rs[j] += __shfl_xor(rs[j], off);
        }
        if ((lane & 15) == 0) {
            size_t r = rowg + m * 16 + (lane >> 4) * 4;
            #pragma unroll
            for (int j = 0; j < 4; ++j) atomicAdd(&scores[r + j], rs[j]);
        }
    }
}

// ---------- fallback epilogue (4-wave kernel) ----------
__device__ __forceinline__ void score_epilogue(
    f32x4 acc[4][4], int n0, int wm, int wn, int lane, size_t row0,
    const float* __restrict__ decp, const float* __restrict__ covp,
    const float* __restrict__ V, float* __restrict__ scores)
{
    int colb = n0 + wn * 64 + (lane & 15);
    size_t rowg = row0 + (size_t)wm * 64;
    int b = (int)(rowg >> 11);
    float cb = covp[b];
    float vv[4], dp[4];
    #pragma unroll
    for (int n = 0; n < 4; ++n) {
        int c = colb + n * 16;
        vv[n] = V[c];
        dp[n] = decp[b * H_ + c] + cb;
    }
    #pragma unroll
    for (int m = 0; m < 4; ++m) {
        float rs[4] = {0.f, 0.f, 0.f, 0.f};
        #pragma unroll
        for (int n = 0; n < 4; ++n) {
            f32x4 A = acc[m][n];
            #pragma unroll
            for (int j = 0; j < 4; ++j) {
                float x = A[j] + dp[n];
                float e = __expf(2.f * x);
                float th = 1.f - 2.f / (e + 1.f);
                rs[j] += th * vv[n];
            }
        }
        #pragma unroll
        for (int off = 1; off < 16; off <<= 1) {
            #pragma unroll
            for (int j = 0; j < 4; ++j) rs[j] += __shfl_xor(rs[j], off);
        }
        if ((lane & 15) == 0) {
            size_t r = rowg + m * 16 + (lane >> 4) * 4;
            #pragma unroll
            for (int j = 0; j < 4; ++j) atomicAdd(&scores[r + j], rs[j]);
        }
    }
}

// ---------- fallback GEMM (fp32 A reg-staged, 128^2) ----------
__global__ __launch_bounds__(256, 2) void k_gemm_stage32(
    const float* __restrict__ enc, const unsigned short* __restrict__ whT,
    const float* __restrict__ decp, const float* __restrict__ covp,
    const float* __restrict__ V, float* __restrict__ scores)
{
    __shared__ uint4 lds[2][1024];
    int bid = blockIdx.x;
    int xcd = bid & 7, idx = bid >> 3;
    int tile_m = xcd * 64 + (idx >> 3);
    int tile_n = idx & 7;
    int t = threadIdx.x, lane = t & 63, wid = t >> 6;
    int wm = wid >> 1, wn = wid & 1;
    size_t row0 = (size_t)tile_m * 128;
    int n0 = tile_n * 128;
    int c0 = t, c1 = t + 256;
    int blk0 = c0 >> 6, l0 = c0 & 63, r0 = blk0 * 16 + (l0 & 15), ks0 = l0 >> 4;
    int blk1 = c1 >> 6, l1 = c1 & 63, r1 = blk1 * 16 + (l1 & 15), ks1 = l1 >> 4;
    const float* pa0 = enc + (row0 + r0) * H_ + ks0 * 8;
    const float* pa1 = enc + (row0 + r1) * H_ + ks1 * 8;
    const unsigned short* pb0 = whT + (size_t)(n0 + r0) * H_ + ks0 * 8;
    const unsigned short* pb1 = whT + (size_t)(n0 + r1) * H_ + ks1 * 8;
    f32x4 acc[4][4] = {};
    float4 a0x, a0y, a1x, a1y;
    uint4 b0, b1;
    auto LOAD = [&](int kt) {
        const float4* q0 = (const float4*)(pa0 + kt * 32);
        a0x = q0[0]; a0y = q0[1];
        const float4* q1 = (const float4*)(pa1 + kt * 32);
        a1x = q1[0]; a1y = q1[1];
        b0 = *(const uint4*)(pb0 + kt * 32);
        b1 = *(const uint4*)(pb1 + kt * 32);
    };
    auto WRITE = [&](int buf) {
        lds[buf][c0] = make_uint4(pk2(a0x.x, a0x.y), pk2(a0x.z, a0x.w),
                                  pk2(a0y.x, a0y.y), pk2(a0y.z, a0y.w));
        lds[buf][c1] = make_uint4(pk2(a1x.x, a1x.y), pk2(a1x.z, a1x.w),
                                  pk2(a1y.x, a1y.y), pk2(a1y.z, a1y.w));
        lds[buf][512 + c0] = b0;
        lds[buf][512 + c1] = b1;
    };
    LOAD(0); WRITE(0); __syncthreads();
    int cur = 0;
    for (int kt = 0; kt < 32; ++kt) {
        if (kt < 31) LOAD(kt + 1);
        const short8* LA = (const short8*)&lds[cur][0];
        const short8* LB = (const short8*)&lds[cur][512];
        short8 af[4], bf[4];
        #pragma unroll
        for (int m = 0; m < 4; ++m) af[m] = LA[(wm * 4 + m) * 64 + lane];
        #pragma unroll
        for (int n = 0; n < 4; ++n) bf[n] = LB[(wn * 4 + n) * 64 + lane];
        #pragma unroll
        for (int m = 0; m < 4; ++m)
            #pragma unroll
            for (int n = 0; n < 4; ++n)
                acc[m][n] = __builtin_amdgcn_mfma_f32_16x16x32_bf16(af[m], bf[n], acc[m][n], 0, 0, 0);
        if (kt < 31) WRITE(cur ^ 1);
        __syncthreads();
        cur ^= 1;
    }
    score_epilogue(acc, n0, wm, wn, lane, row0, decp, covp, V, scores);
}

// ---------- softmax over S per b; writes attn and coverage_new ----------
__global__ void k_softmax(const float* __restrict__ scores, const float* __restrict__ cov,
                          float* __restrict__ out) {
    int b = blockIdx.x, t = threadIdx.x;
    float* attn = out + B_ * H_;
    float* covn = out + B_ * H_ + B_ * S_;
    float v[8];
    float mx = -1e30f;
    #pragma unroll
    for (int i = 0; i < 8; ++i) {
        v[i] = scores[b * S_ + i * 256 + t];
        mx = fmaxf(mx, v[i]);
    }
    for (int off = 32; off; off >>= 1) mx = fmaxf(mx, __shfl_xor(mx, off));
    __shared__ float wsm[4], wss[4];
    if ((t & 63) == 0) wsm[t >> 6] = mx;
    __syncthreads();
    mx = fmaxf(fmaxf(wsm[0], wsm[1]), fmaxf(wsm[2], wsm[3]));
    float sum = 0.f;
    #pragma unroll
    for (int i = 0; i < 8; ++i) { v[i] = __expf(v[i] - mx); sum += v[i]; }
    for (int off = 32; off; off >>= 1) sum += __shfl_xor(sum, off);
    if ((t & 63) == 0) wss[t >> 6] = sum;
    __syncthreads();
    sum = wss[0] + wss[1] + wss[2] + wss[3];
    float inv = 1.f / sum;
    #pragma unroll
    for (int i = 0; i < 8; ++i) {
        int s = i * 256 + t;
        float a = v[i] * inv;
        attn[b * S_ + s] = a;
        covn[b * S_ + s] = cov[b * S_ + s] + a;
    }
}

// ---------- context from bf16 enc ----------
__global__ void k_context_bf(const unsigned short* __restrict__ encBF,
                             const float* __restrict__ attn, float* __restrict__ ctx) {
    int b = blockIdx.y, chunk = blockIdx.x; // 16 chunks x 128 s
    int t = threadIdx.x;
    __shared__ float sa[128];
    int s0 = chunk * 128;
    if (t < 128) sa[t] = attn[b * S_ + s0 + t];
    __syncthreads();
    float4 acc = {0.f, 0.f, 0.f, 0.f};
    const unsigned short* e = encBF + ((size_t)(b * S_ + s0)) * H_ + t * 4;
    #pragma unroll 4
    for (int s = 0; s < 128; ++s) {
        u16x4 x = *(const u16x4*)(e + (size_t)s * H_);
        float a = sa[s];
        acc.x += a * bf2f(x[0]); acc.y += a * bf2f(x[1]);
        acc.z += a * bf2f(x[2]); acc.w += a * bf2f(x[3]);
    }
    float* c = ctx + b * H_ + t * 4;
    atomicAdd(c + 0, acc.x); atomicAdd(c + 1, acc.y);
    atomicAdd(c + 2, acc.z); atomicAdd(c + 3, acc.w);
}

// ---------- context from fp32 enc (fallback) ----------
__global__ void k_context_f32(const float* __restrict__ enc, const float* __restrict__ attn,
                              float* __restrict__ ctx) {
    int b = blockIdx.y, chunk = blockIdx.x;
    int t = threadIdx.x;
    __shared__ float sa[128];
    int s0 = chunk * 128;
    if (t < 128) sa[t] = attn[b * S_ + s0 + t];
    __syncthreads();
    float4 acc = {0.f, 0.f, 0.f, 0.f};
    const float4* e = (const float4*)(enc + ((size_t)b * S_ + s0) * H_) + t;
    #pragma unroll 4
    for (int s = 0; s < 128; ++s) {
        float4 x = e[(size_t)s * (H_ / 4)];
        float a = sa[s];
        acc.x += a * x.x; acc.y += a * x.y; acc.z += a * x.z; acc.w += a * x.w;
    }
    float* c = ctx + b * H_ + t * 4;
    atomicAdd(c + 0, acc.x); atomicAdd(c + 1, acc.y);
    atomicAdd(c + 2, acc.z); atomicAdd(c + 3, acc.w);
}

extern "C" void kernel_launch(void* const* d_in, const int* in_sizes, int n_in,
                              void* d_out, int out_size, void* d_ws, size_t ws_size,
                              hipStream_t stream) {
    (void)in_sizes; (void)n_in; (void)out_size;
    const float* ds  = (const float*)d_in[0];
    const float* enc = (const float*)d_in[1];
    const float* cov = (const float*)d_in[2];
    const float* Wh  = (const float*)d_in[3];
    const float* bh  = (const float*)d_in[4];
    const float* Ws  = (const float*)d_in[5];
    const float* bs  = (const float*)d_in[6];
    const float* V   = (const float*)d_in[7];
    // d_in[8] = bv: softmax-invariant constant -> unused
    const float* Wc  = (const float*)d_in[9];
    const float* bc  = (const float*)d_in[10];
    float* out = (float*)d_out;

    float* ws_scores = (float*)d_ws;                          // 65536 f32
    float* ws_decp   = ws_scores + B_ * S_;                   // 32768 f32
    float* ws_covp   = ws_decp + B_ * H_;                     // 64 f32
    unsigned short* ws_whT = (unsigned short*)(ws_covp + 64); // 1M bf16 (2MB)
    unsigned short* ws_encBF = ws_whT + (size_t)H_ * H_;      // 64M bf16 (128MB)
    const size_t need_full = ((char*)(ws_encBF + (size_t)B_ * S_ * H_)) - (char*)d_ws;

    hipMemsetAsync(ws_scores, 0, B_ * S_ * sizeof(float), stream);
    hipMemsetAsync(out, 0, B_ * H_ * sizeof(float), stream); // context accumulators

    k_whT<<<dim3(16, 16), dim3(64, 4), 0, stream>>>(Wh, ws_whT);
    k_decp<<<dim3(4, 32), 256, 0, stream>>>(ds, Ws, bs, bh, ws_decp);
    k_covp<<<32, 256, 0, stream>>>(cov, Wc, bc, ws_covp);

    if (ws_size >= need_full) {
        k_cvt<<<2048, 256, 0, stream>>>(enc, (uint4*)ws_encBF, (B_ * S_ * H_) / 8);
        k_gemm_8w<<<1024, 512, 0, stream>>>(ws_encBF, ws_whT, ws_decp, ws_covp, V, ws_scores);
        k_softmax<<<32, 256, 0, stream>>>(ws_scores, cov, out);
        k_context_bf<<<dim3(16, 32), 256, 0, stream>>>(ws_encBF, out + B_ * H_, out);
    } else {
        k_gemm_stage32<<<4096, 256, 0, stream>>>(enc, ws_whT, ws_decp, ws_covp, V, ws_scores);
        k_softmax<<<32, 256, 0, stream>>>(ws_scores, cov, out);
        k_context_f32<<<dim3(16, 32), 256, 0, stream>>>(enc, out + B_ * H_, out);
    }
}

// Round 4
// 337.821 us; speedup vs baseline: 1.4230x; 1.0076x over previous
//
#include <hip/hip_runtime.h>

#define B_ 32
#define S_ 2048
#define H_ 1024

typedef __attribute__((ext_vector_type(8))) short short8;
typedef __attribute__((ext_vector_type(4))) float f32x4;
typedef __attribute__((ext_vector_type(4))) unsigned short u16x4;

__device__ __forceinline__ unsigned short f2bf(float f) {
    unsigned u = __builtin_bit_cast(unsigned, f);
    u += 0x7FFFu + ((u >> 16) & 1u);
    return (unsigned short)(u >> 16);
}
__device__ __forceinline__ unsigned pk2(float x, float y) {
    return (unsigned)f2bf(x) | ((unsigned)f2bf(y) << 16);
}
__device__ __forceinline__ float bf2f(unsigned short u) {
    unsigned x = ((unsigned)u) << 16;
    return __builtin_bit_cast(float, x);
}
__device__ __forceinline__ void gload16(const void* g, void* l) {
    __builtin_amdgcn_global_load_lds((const __attribute__((address_space(1))) void*)g,
                                     (__attribute__((address_space(3))) void*)l, 16, 0, 0);
}

#define WAITV(nstr) asm volatile("s_waitcnt vmcnt(" nstr ")" ::: "memory")

// ---------- enc fp32 -> bf16 ----------
__global__ void k_cvt(const float* __restrict__ in, uint4* __restrict__ out, int ngroups) {
    int i = blockIdx.x * blockDim.x + threadIdx.x;
    int stride = gridDim.x * blockDim.x;
    for (; i < ngroups; i += stride) {
        const float4* p = (const float4*)in + (size_t)i * 2;
        float4 x = p[0], y = p[1];
        out[i] = make_uint4(pk2(x.x, x.y), pk2(x.z, x.w), pk2(y.x, y.y), pk2(y.z, y.w));
    }
}

// ---------- prep: Wh (K,N) fp32 -> WhT (N,K) bf16 ----------
__global__ void k_whT(const float* __restrict__ Wh, unsigned short* __restrict__ whT) {
    __shared__ float tile[64][65];
    int k0 = blockIdx.x * 64, n0 = blockIdx.y * 64;
    int tx = threadIdx.x, ty = threadIdx.y; // (64,4)
    #pragma unroll
    for (int i = 0; i < 16; ++i) {
        int r = ty + i * 4;
        tile[r][tx] = Wh[(size_t)(k0 + r) * H_ + n0 + tx];
    }
    __syncthreads();
    #pragma unroll
    for (int i = 0; i < 16; ++i) {
        int r = ty + i * 4;
        whT[(size_t)(n0 + r) * H_ + k0 + tx] = f2bf(tile[tx][r]);
    }
}

// ---------- prep: decp[b][n] = ds[b]@Ws[:,n] + bs[n] + bh[n] ----------
__global__ void k_decp(const float* __restrict__ ds, const float* __restrict__ Ws,
                       const float* __restrict__ bs, const float* __restrict__ bh,
                       float* __restrict__ decp) {
    int n = blockIdx.x * 256 + threadIdx.x;
    int b = blockIdx.y;
    float a0 = 0.f, a1 = 0.f, a2 = 0.f, a3 = 0.f;
    for (int h = 0; h < H_; h += 4) {
        a0 += ds[b * H_ + h + 0] * Ws[(size_t)(h + 0) * H_ + n];
        a1 += ds[b * H_ + h + 1] * Ws[(size_t)(h + 1) * H_ + n];
        a2 += ds[b * H_ + h + 2] * Ws[(size_t)(h + 2) * H_ + n];
        a3 += ds[b * H_ + h + 3] * Ws[(size_t)(h + 3) * H_ + n];
    }
    decp[b * H_ + n] = a0 + a1 + a2 + a3 + bs[n] + bh[n];
}

// ---------- prep: covp[b] = cov[b]@Wc + bc ----------
__global__ void k_covp(const float* __restrict__ cov, const float* __restrict__ Wc,
                       const float* __restrict__ bc, float* __restrict__ covp) {
    int b = blockIdx.x, t = threadIdx.x;
    float p = 0.f;
    for (int s = t; s < S_; s += 256) p += cov[b * S_ + s] * Wc[s];
    for (int off = 32; off; off >>= 1) p += __shfl_down(p, off);
    __shared__ float w[4];
    if ((t & 63) == 0) w[t >> 6] = p;
    __syncthreads();
    if (t == 0) covp[b] = w[0] + w[1] + w[2] + w[3] + bc[0];
}

// ---------- main GEMM: 256x256 tile, 8 waves, BK=64, 8-phase counted-vmcnt ----------
// LDS: 4 half-buffers x 32KB (A 16KB | B 16KB). Half h covers k = h*32..h*32+32.
// Chunk (1KB) = 16 rows x 32 k, lane-linear: lane l <-> (row 16c+(l&15), k (l>>4)*8..+8).
// Per K-tile (2 halves): 4 phases, each {4-8 ds_read_b128 | 2 gload_lds issues |
// barrier | setprio(1) 16 MFMA setprio(0) | barrier}; vmcnt(8) twice per K-tile.
// In-flight: 3 half-tiles (12 loads/thread); vmcnt never drains to 0 until tail.
__global__ __launch_bounds__(512, 2) void k_gemm_8p(
    const unsigned short* __restrict__ A, const unsigned short* __restrict__ Bm,
    const float* __restrict__ decp, const float* __restrict__ covp,
    const float* __restrict__ V, float* __restrict__ scores)
{
    __shared__ char lds[131072];

    int bid = blockIdx.x;
    // bijective XCD-chunked swizzle (1024 % 8 == 0): the 4 n-tiles sharing an
    // A-stripe are consecutive within one XCD's chunk.
    int xcd = bid & 7, local = bid >> 3;
    int T = xcd * 128 + local;
    int tile_m = T >> 2, tile_n = T & 3;
    size_t row0 = (size_t)tile_m * 256;
    int n0 = tile_n * 256;

    int t = threadIdx.x, lane = t & 63, wid = t >> 6; // 8 waves
    int wm = wid >> 2, wn = wid & 3;                  // 2 x 4 wave grid
    int lrow = lane & 15, lk = (lane >> 4) * 8;

    // wave w stages chunks {2w,2w+1} (rows 32w..32w+31) per half, A and B alike
    const unsigned short* gA0 = A + (row0 + (size_t)(wid * 32) + lrow) * H_ + lk;
    const unsigned short* gA1 = gA0 + (size_t)16 * H_;
    const unsigned short* gB0 = Bm + ((size_t)(n0 + wid * 32 + lrow)) * H_ + lk;
    const unsigned short* gB1 = gB0 + (size_t)16 * H_;

    f32x4 acc[8][4] = {};
    short8 bfr[4];

    auto stA = [&](int h) { // stage A part of half h (k = h*32)
        char* lb = lds + (h & 3) * 32768;
        gload16(gA0 + h * 32, lb + (2 * wid) * 1024);
        gload16(gA1 + h * 32, lb + (2 * wid + 1) * 1024);
    };
    auto stB = [&](int h) {
        char* lb = lds + (h & 3) * 32768 + 16384;
        gload16(gB0 + h * 32, lb + (2 * wid) * 1024);
        gload16(gB1 + h * 32, lb + (2 * wid + 1) * 1024);
    };

// one phase: m-half MH (0/1) of half-tile h; ISSUE = staging statement or (void)0
#define PHASE(h, MH, ISSUE) do { \
    const char* hb_ = lds + ((h) & 3) * 32768; \
    short8 af_[4]; \
    af_[0] = *(const short8*)(hb_ + (wm * 8 + (MH)*4 + 0) * 1024 + lane * 16); \
    af_[1] = *(const short8*)(hb_ + (wm * 8 + (MH)*4 + 1) * 1024 + lane * 16); \
    af_[2] = *(const short8*)(hb_ + (wm * 8 + (MH)*4 + 2) * 1024 + lane * 16); \
    af_[3] = *(const short8*)(hb_ + (wm * 8 + (MH)*4 + 3) * 1024 + lane * 16); \
    if ((MH) == 0) { \
        bfr[0] = *(const short8*)(hb_ + 16384 + (wn * 4 + 0) * 1024 + lane * 16); \
        bfr[1] = *(const short8*)(hb_ + 16384 + (wn * 4 + 1) * 1024 + lane * 16); \
        bfr[2] = *(const short8*)(hb_ + 16384 + (wn * 4 + 2) * 1024 + lane * 16); \
        bfr[3] = *(const short8*)(hb_ + 16384 + (wn * 4 + 3) * 1024 + lane * 16); \
    } \
    ISSUE; \
    __builtin_amdgcn_s_barrier(); \
    __builtin_amdgcn_s_setprio(1); \
    _Pragma("unroll") \
    for (int i_ = 0; i_ < 4; ++i_) { \
        acc[(MH)*4 + i_][0] = __builtin_amdgcn_mfma_f32_16x16x32_bf16(af_[i_], bfr[0], acc[(MH)*4 + i_][0], 0, 0, 0); \
        acc[(MH)*4 + i_][1] = __builtin_amdgcn_mfma_f32_16x16x32_bf16(af_[i_], bfr[1], acc[(MH)*4 + i_][1], 0, 0, 0); \
        acc[(MH)*4 + i_][2] = __builtin_amdgcn_mfma_f32_16x16x32_bf16(af_[i_], bfr[2], acc[(MH)*4 + i_][2], 0, 0, 0); \
        acc[(MH)*4 + i_][3] = __builtin_amdgcn_mfma_f32_16x16x32_bf16(af_[i_], bfr[3], acc[(MH)*4 + i_][3], 0, 0, 0); \
    } \
    __builtin_amdgcn_s_setprio(0); \
    __builtin_amdgcn_s_barrier(); \
} while (0)

    // prologue: halves 0,1,2 in flight (12 loads/thread)
    stA(0); stB(0); stA(1); stB(1); stA(2); stB(2);

    for (int tt = 0; tt < 14; ++tt) {
        int h0 = 2 * tt, h1 = 2 * tt + 1;
        WAITV("8"); __builtin_amdgcn_s_barrier();      // half h0 landed (h0+1,h0+2 in flight)
        PHASE(h0, 0, stA(h1 + 2));                     // issue A of half 2tt+3
        PHASE(h0, 1, stB(h1 + 2));
        WAITV("8"); __builtin_amdgcn_s_barrier();      // half h1 landed
        PHASE(h1, 0, stA(h1 + 3));                     // issue A of half 2tt+4
        PHASE(h1, 1, stB(h1 + 3));
    }
    // tt=14: only half 31 left to issue
    WAITV("8"); __builtin_amdgcn_s_barrier();
    PHASE(28, 0, stA(31));
    PHASE(28, 1, stB(31));
    WAITV("8"); __builtin_amdgcn_s_barrier();
    PHASE(29, 0, (void)0);
    PHASE(29, 1, (void)0);
    // tt=15: drain
    WAITV("4"); __builtin_amdgcn_s_barrier();
    PHASE(30, 0, (void)0);
    PHASE(30, 1, (void)0);
    WAITV("0"); __builtin_amdgcn_s_barrier();
    PHASE(31, 0, (void)0);
    PHASE(31, 1, (void)0);
#undef PHASE

    // ---- epilogue: tanh + V-dot + 16-lane reduce + atomicAdd ----
    int colb = n0 + wn * 64 + (lane & 15);
    size_t rowg = row0 + (size_t)wm * 128;
    int b = (int)(row0 >> 11); // block entirely within one batch (2048 % 256 == 0)
    float cb = covp[b];
    float vv[4], dp[4];
    #pragma unroll
    for (int n = 0; n < 4; ++n) {
        int c = colb + n * 16;
        vv[n] = V[c];
        dp[n] = decp[b * H_ + c] + cb;
    }
    #pragma unroll
    for (int m = 0; m < 8; ++m) {
        float rs[4] = {0.f, 0.f, 0.f, 0.f};
        #pragma unroll
        for (int n = 0; n < 4; ++n) {
            f32x4 Aq = acc[m][n];
            #pragma unroll
            for (int j = 0; j < 4; ++j) {
                float x = Aq[j] + dp[n];
                float e = __expf(2.f * x);
                float th = 1.f - 2.f / (e + 1.f); // inf-safe tanh
                rs[j] += th * vv[n];
            }
        }
        #pragma unroll
        for (int off = 1; off < 16; off <<= 1) {
            #pragma unroll
            for (int j = 0; j < 4; ++j) rs[j] += __shfl_xor(rs[j], off);
        }
        if ((lane & 15) == 0) {
            size_t r = rowg + m * 16 + (lane >> 4) * 4;
            #pragma unroll
            for (int j = 0; j < 4; ++j) atomicAdd(&scores[r + j], rs[j]);
        }
    }
}

// ---------- fallback epilogue (4-wave kernel) ----------
__device__ __forceinline__ void score_epilogue(
    f32x4 acc[4][4], int n0, int wm, int wn, int lane, size_t row0,
    const float* __restrict__ decp, const float* __restrict__ covp,
    const float* __restrict__ V, float* __restrict__ scores)
{
    int colb = n0 + wn * 64 + (lane & 15);
    size_t rowg = row0 + (size_t)wm * 64;
    int b = (int)(rowg >> 11);
    float cb = covp[b];
    float vv[4], dp[4];
    #pragma unroll
    for (int n = 0; n < 4; ++n) {
        int c = colb + n * 16;
        vv[n] = V[c];
        dp[n] = decp[b * H_ + c] + cb;
    }
    #pragma unroll
    for (int m = 0; m < 4; ++m) {
        float rs[4] = {0.f, 0.f, 0.f, 0.f};
        #pragma unroll
        for (int n = 0; n < 4; ++n) {
            f32x4 A = acc[m][n];
            #pragma unroll
            for (int j = 0; j < 4; ++j) {
                float x = A[j] + dp[n];
                float e = __expf(2.f * x);
                float th = 1.f - 2.f / (e + 1.f);
                rs[j] += th * vv[n];
            }
        }
        #pragma unroll
        for (int off = 1; off < 16; off <<= 1) {
            #pragma unroll
            for (int j = 0; j < 4; ++j) rs[j] += __shfl_xor(rs[j], off);
        }
        if ((lane & 15) == 0) {
            size_t r = rowg + m * 16 + (lane >> 4) * 4;
            #pragma unroll
            for (int j = 0; j < 4; ++j) atomicAdd(&scores[r + j], rs[j]);
        }
    }
}

// ---------- fallback GEMM (fp32 A reg-staged, 128^2) ----------
__global__ __launch_bounds__(256, 2) void k_gemm_stage32(
    const float* __restrict__ enc, const unsigned short* __restrict__ whT,
    const float* __restrict__ decp, const float* __restrict__ covp,
    const float* __restrict__ V, float* __restrict__ scores)
{
    __shared__ uint4 lds[2][1024];
    int bid = blockIdx.x;
    int xcd = bid & 7, idx = bid >> 3;
    int tile_m = xcd * 64 + (idx >> 3);
    int tile_n = idx & 7;
    int t = threadIdx.x, lane = t & 63, wid = t >> 6;
    int wm = wid >> 1, wn = wid & 1;
    size_t row0 = (size_t)tile_m * 128;
    int n0 = tile_n * 128;
    int c0 = t, c1 = t + 256;
    int blk0 = c0 >> 6, l0 = c0 & 63, r0 = blk0 * 16 + (l0 & 15), ks0 = l0 >> 4;
    int blk1 = c1 >> 6, l1 = c1 & 63, r1 = blk1 * 16 + (l1 & 15), ks1 = l1 >> 4;
    const float* pa0 = enc + (row0 + r0) * H_ + ks0 * 8;
    const float* pa1 = enc + (row0 + r1) * H_ + ks1 * 8;
    const unsigned short* pb0 = whT + (size_t)(n0 + r0) * H_ + ks0 * 8;
    const unsigned short* pb1 = whT + (size_t)(n0 + r1) * H_ + ks1 * 8;
    f32x4 acc[4][4] = {};
    float4 a0x, a0y, a1x, a1y;
    uint4 b0, b1;
    auto LOAD = [&](int kt) {
        const float4* q0 = (const float4*)(pa0 + kt * 32);
        a0x = q0[0]; a0y = q0[1];
        const float4* q1 = (const float4*)(pa1 + kt * 32);
        a1x = q1[0]; a1y = q1[1];
        b0 = *(const uint4*)(pb0 + kt * 32);
        b1 = *(const uint4*)(pb1 + kt * 32);
    };
    auto WRITE = [&](int buf) {
        lds[buf][c0] = make_uint4(pk2(a0x.x, a0x.y), pk2(a0x.z, a0x.w),
                                  pk2(a0y.x, a0y.y), pk2(a0y.z, a0y.w));
        lds[buf][c1] = make_uint4(pk2(a1x.x, a1x.y), pk2(a1x.z, a1x.w),
                                  pk2(a1y.x, a1y.y), pk2(a1y.z, a1y.w));
        lds[buf][512 + c0] = b0;
        lds[buf][512 + c1] = b1;
    };
    LOAD(0); WRITE(0); __syncthreads();
    int cur = 0;
    for (int kt = 0; kt < 32; ++kt) {
        if (kt < 31) LOAD(kt + 1);
        const short8* LA = (const short8*)&lds[cur][0];
        const short8* LB = (const short8*)&lds[cur][512];
        short8 af[4], bf[4];
        #pragma unroll
        for (int m = 0; m < 4; ++m) af[m] = LA[(wm * 4 + m) * 64 + lane];
        #pragma unroll
        for (int n = 0; n < 4; ++n) bf[n] = LB[(wn * 4 + n) * 64 + lane];
        #pragma unroll
        for (int m = 0; m < 4; ++m)
            #pragma unroll
            for (int n = 0; n < 4; ++n)
                acc[m][n] = __builtin_amdgcn_mfma_f32_16x16x32_bf16(af[m], bf[n], acc[m][n], 0, 0, 0);
        if (kt < 31) WRITE(cur ^ 1);
        __syncthreads();
        cur ^= 1;
    }
    score_epilogue(acc, n0, wm, wn, lane, row0, decp, covp, V, scores);
}

// ---------- softmax over S per b; writes attn and coverage_new ----------
__global__ void k_softmax(const float* __restrict__ scores, const float* __restrict__ cov,
                          float* __restrict__ out) {
    int b = blockIdx.x, t = threadIdx.x;
    float* attn = out + B_ * H_;
    float* covn = out + B_ * H_ + B_ * S_;
    float v[8];
    float mx = -1e30f;
    #pragma unroll
    for (int i = 0; i < 8; ++i) {
        v[i] = scores[b * S_ + i * 256 + t];
        mx = fmaxf(mx, v[i]);
    }
    for (int off = 32; off; off >>= 1) mx = fmaxf(mx, __shfl_xor(mx, off));
    __shared__ float wsm[4], wss[4];
    if ((t & 63) == 0) wsm[t >> 6] = mx;
    __syncthreads();
    mx = fmaxf(fmaxf(wsm[0], wsm[1]), fmaxf(wsm[2], wsm[3]));
    float sum = 0.f;
    #pragma unroll
    for (int i = 0; i < 8; ++i) { v[i] = __expf(v[i] - mx); sum += v[i]; }
    for (int off = 32; off; off >>= 1) sum += __shfl_xor(sum, off);
    if ((t & 63) == 0) wss[t >> 6] = sum;
    __syncthreads();
    sum = wss[0] + wss[1] + wss[2] + wss[3];
    float inv = 1.f / sum;
    #pragma unroll
    for (int i = 0; i < 8; ++i) {
        int s = i * 256 + t;
        float a = v[i] * inv;
        attn[b * S_ + s] = a;
        covn[b * S_ + s] = cov[b * S_ + s] + a;
    }
}

// ---------- context from bf16 enc ----------
__global__ void k_context_bf(const unsigned short* __restrict__ encBF,
                             const float* __restrict__ attn, float* __restrict__ ctx) {
    int b = blockIdx.y, chunk = blockIdx.x; // 16 chunks x 128 s
    int t = threadIdx.x;
    __shared__ float sa[128];
    int s0 = chunk * 128;
    if (t < 128) sa[t] = attn[b * S_ + s0 + t];
    __syncthreads();
    float4 acc = {0.f, 0.f, 0.f, 0.f};
    const unsigned short* e = encBF + ((size_t)(b * S_ + s0)) * H_ + t * 4;
    #pragma unroll 4
    for (int s = 0; s < 128; ++s) {
        u16x4 x = *(const u16x4*)(e + (size_t)s * H_);
        float a = sa[s];
        acc.x += a * bf2f(x[0]); acc.y += a * bf2f(x[1]);
        acc.z += a * bf2f(x[2]); acc.w += a * bf2f(x[3]);
    }
    float* c = ctx + b * H_ + t * 4;
    atomicAdd(c + 0, acc.x); atomicAdd(c + 1, acc.y);
    atomicAdd(c + 2, acc.z); atomicAdd(c + 3, acc.w);
}

// ---------- context from fp32 enc (fallback) ----------
__global__ void k_context_f32(const float* __restrict__ enc, const float* __restrict__ attn,
                              float* __restrict__ ctx) {
    int b = blockIdx.y, chunk = blockIdx.x;
    int t = threadIdx.x;
    __shared__ float sa[128];
    int s0 = chunk * 128;
    if (t < 128) sa[t] = attn[b * S_ + s0 + t];
    __syncthreads();
    float4 acc = {0.f, 0.f, 0.f, 0.f};
    const float4* e = (const float4*)(enc + ((size_t)b * S_ + s0) * H_) + t;
    #pragma unroll 4
    for (int s = 0; s < 128; ++s) {
        float4 x = e[(size_t)s * (H_ / 4)];
        float a = sa[s];
        acc.x += a * x.x; acc.y += a * x.y; acc.z += a * x.z; acc.w += a * x.w;
    }
    float* c = ctx + b * H_ + t * 4;
    atomicAdd(c + 0, acc.x); atomicAdd(c + 1, acc.y);
    atomicAdd(c + 2, acc.z); atomicAdd(c + 3, acc.w);
}

extern "C" void kernel_launch(void* const* d_in, const int* in_sizes, int n_in,
                              void* d_out, int out_size, void* d_ws, size_t ws_size,
                              hipStream_t stream) {
    (void)in_sizes; (void)n_in; (void)out_size;
    const float* ds  = (const float*)d_in[0];
    const float* enc = (const float*)d_in[1];
    const float* cov = (const float*)d_in[2];
    const float* Wh  = (const float*)d_in[3];
    const float* bh  = (const float*)d_in[4];
    const float* Ws  = (const float*)d_in[5];
    const float* bs  = (const float*)d_in[6];
    const float* V   = (const float*)d_in[7];
    // d_in[8] = bv: softmax-invariant constant -> unused
    const float* Wc  = (const float*)d_in[9];
    const float* bc  = (const float*)d_in[10];
    float* out = (float*)d_out;

    float* ws_scores = (float*)d_ws;                          // 65536 f32
    float* ws_decp   = ws_scores + B_ * S_;                   // 32768 f32
    float* ws_covp   = ws_decp + B_ * H_;                     // 64 f32
    unsigned short* ws_whT = (unsigned short*)(ws_covp + 64); // 1M bf16 (2MB)
    unsigned short* ws_encBF = ws_whT + (size_t)H_ * H_;      // 64M bf16 (128MB)
    const size_t need_full = ((char*)(ws_encBF + (size_t)B_ * S_ * H_)) - (char*)d_ws;

    hipMemsetAsync(ws_scores, 0, B_ * S_ * sizeof(float), stream);
    hipMemsetAsync(out, 0, B_ * H_ * sizeof(float), stream); // context accumulators

    k_whT<<<dim3(16, 16), dim3(64, 4), 0, stream>>>(Wh, ws_whT);
    k_decp<<<dim3(4, 32), 256, 0, stream>>>(ds, Ws, bs, bh, ws_decp);
    k_covp<<<32, 256, 0, stream>>>(cov, Wc, bc, ws_covp);

    if (ws_size >= need_full) {
        k_cvt<<<2048, 256, 0, stream>>>(enc, (uint4*)ws_encBF, (B_ * S_ * H_) / 8);
        k_gemm_8p<<<1024, 512, 0, stream>>>(ws_encBF, ws_whT, ws_decp, ws_covp, V, ws_scores);
        k_softmax<<<32, 256, 0, stream>>>(ws_scores, cov, out);
        k_context_bf<<<dim3(16, 32), 256, 0, stream>>>(ws_encBF, out + B_ * H_, out);
    } else {
        k_gemm_stage32<<<4096, 256, 0, stream>>>(enc, ws_whT, ws_decp, ws_covp, V, ws_scores);
        k_softmax<<<32, 256, 0, stream>>>(ws_scores, cov, out);
        k_context_f32<<<dim3(16, 32), 256, 0, stream>>>(enc, out + B_ * H_, out);
    }
}